// Round 12
// baseline (140.901 us; speedup 1.0000x reference)
//
#include <hip/hip_runtime.h>
#include <stdint.h>

// out = coeff_res(t) * x + [coeff_pre(t)*coeff_post(t)] * (x @ W_sub)
// coeffs from gates = LN(x) @ proj_w^T + proj_b  (48/token), softmax sums + 4x4 Cayley.

typedef __attribute__((ext_vector_type(8))) __bf16 bf16x8;
typedef __attribute__((ext_vector_type(4))) float f32x4;
typedef __attribute__((ext_vector_type(8))) unsigned short us8;
typedef __attribute__((ext_vector_type(4))) unsigned short us4;

__device__ __forceinline__ unsigned short f2bf(float f) {
  union { float f; unsigned int u; } v; v.f = f;
  unsigned int u = v.u;
  u += 0x7fffu + ((u >> 16) & 1u);   // RNE
  return (unsigned short)(u >> 16);
}

__device__ __forceinline__ float bf2f(unsigned short u) {
  union { unsigned int u; float f; } v; v.u = (unsigned int)u << 16;
  return v.f;
}

__device__ __forceinline__ void gload_lds16(const void* g, void* l) {
  __builtin_amdgcn_global_load_lds(
      (__attribute__((address_space(1))) void*)g,
      (__attribute__((address_space(3))) void*)l, 16, 0, 0);
}

// K1: per-token LayerNorm stats + write x_bf16 and ln_bf16
__global__ __launch_bounds__(256) void k_ln_conv(
    const float* __restrict__ x, const float* __restrict__ lw, const float* __restrict__ lb,
    unsigned short* __restrict__ xb, unsigned short* __restrict__ lnb, int D) {
  const int t = blockIdx.x;
  const int tid = threadIdx.x;
  const float* row = x + (size_t)t * D;
  f32x4 a = *(const f32x4*)(row + tid * 8);
  f32x4 b = *(const f32x4*)(row + tid * 8 + 4);
  float vv[8] = {a[0], a[1], a[2], a[3], b[0], b[1], b[2], b[3]};
  float s = 0.f, ss = 0.f;
#pragma unroll
  for (int j = 0; j < 8; ++j) { s += vv[j]; ss += vv[j] * vv[j]; }
#pragma unroll
  for (int off = 32; off > 0; off >>= 1) { s += __shfl_down(s, off); ss += __shfl_down(ss, off); }
  __shared__ float red[8];
  __shared__ float st[2];
  int lane = tid & 63, wv = tid >> 6;
  if (lane == 0) { red[wv] = s; red[4 + wv] = ss; }
  __syncthreads();
  if (tid == 0) {
    float S = red[0] + red[1] + red[2] + red[3];
    float SS = red[4] + red[5] + red[6] + red[7];
    float mu = S / (float)D;
    float var = SS / (float)D - mu * mu;
    st[0] = mu; st[1] = rsqrtf(var + 1e-5f);
  }
  __syncthreads();
  float mu = st[0], rstd = st[1];
  f32x4 w0 = *(const f32x4*)(lw + tid * 8), w1 = *(const f32x4*)(lw + tid * 8 + 4);
  f32x4 b0 = *(const f32x4*)(lb + tid * 8), b1 = *(const f32x4*)(lb + tid * 8 + 4);
  float ww[8] = {w0[0], w0[1], w0[2], w0[3], w1[0], w1[1], w1[2], w1[3]};
  float bb[8] = {b0[0], b0[1], b0[2], b0[3], b1[0], b1[1], b1[2], b1[3]};
  us8 ox, ol;
#pragma unroll
  for (int j = 0; j < 8; ++j) {
    ox[j] = f2bf(vv[j]);
    ol[j] = f2bf((vv[j] - mu) * rstd * ww[j] + bb[j]);
  }
  *(us8*)(xb + (size_t)t * D + tid * 8) = ox;
  *(us8*)(lnb + (size_t)t * D + tid * 8) = ol;
}

// K2: W_sub [K][N] fp32 -> Wt [N][K] bf16 (tiled transpose)
__global__ __launch_bounds__(256) void k_wt(const float* __restrict__ W,
                                            unsigned short* __restrict__ Wt, int D) {
  __shared__ float tile[64][65];
  int kb = blockIdx.x * 64, nb = blockIdx.y * 64;
  int tid = threadIdx.x;
  int tx = tid & 15, ty = tid >> 4;
#pragma unroll
  for (int p = 0; p < 4; ++p) {
    int r = p * 16 + ty;
    f32x4 v = *(const f32x4*)(W + (size_t)(kb + r) * D + nb + tx * 4);
    tile[r][tx * 4 + 0] = v[0]; tile[r][tx * 4 + 1] = v[1];
    tile[r][tx * 4 + 2] = v[2]; tile[r][tx * 4 + 3] = v[3];
  }
  __syncthreads();
#pragma unroll
  for (int p = 0; p < 2; ++p) {
    int c = p * 256 + tid;
    int nr = c >> 3, kc = (c & 7) * 8;
    us8 o;
#pragma unroll
    for (int j = 0; j < 8; ++j) o[j] = f2bf(tile[kc + j][nr]);
    *(us8*)(Wt + (size_t)(nb + nr) * D + kb + kc) = o;
  }
}

// K2b: proj_w fp32 -> bf16 (layout already [48][K])
__global__ void k_pconv(const float* __restrict__ p, unsigned short* __restrict__ q, int n) {
  int i = (blockIdx.x * 256 + threadIdx.x) * 4;
  if (i < n) {
    f32x4 v = *(const f32x4*)(p + i);
    us4 o;
#pragma unroll
    for (int j = 0; j < 4; ++j) o[j] = f2bf(v[j]);
    *(us4*)(q + i) = o;
  }
}

// K3: gates = ln_bf16 @ projb^T (+pb), then per-token coeff math
__global__ __launch_bounds__(256) void k_gates(
    const unsigned short* __restrict__ A,   // lnb [M][K]
    const unsigned short* __restrict__ Bp,  // pjb [48][K]
    const float* __restrict__ pb,
    float* __restrict__ cresp, float* __restrict__ cpyp, int K) {
  __shared__ __attribute__((aligned(16))) unsigned short As[128 * 32];
  __shared__ __attribute__((aligned(16))) unsigned short Bs[48 * 32];
  __shared__ float gl[128][49];
  __shared__ float pbs[48];
  int tid = threadIdx.x, lane = tid & 63, wv = tid >> 6;
  if (tid < 48) pbs[tid] = pb[tid];
  f32x4 acc[2][3] = {};
  size_t rowBase = (size_t)blockIdx.x * 128;
  for (int k0 = 0; k0 < K; k0 += 32) {
#pragma unroll
    for (int inst = 0; inst < 2; ++inst) {
      int eo = inst * 2048 + wv * 512 + lane * 8;
      int r = eo >> 5, cc = eo & 31;
      gload_lds16(A + (rowBase + r) * K + k0 + cc, (char*)As + inst * 4096 + wv * 1024);
    }
    if (tid < 192) {
      int r = tid >> 2, cc = (tid & 3) * 8;
      us8 v = *(const us8*)(Bp + (size_t)r * K + k0 + cc);
      *(us8*)(Bs + r * 32 + cc) = v;
    }
    __syncthreads();
    int kb = (lane >> 4) * 8, rr = lane & 15;
    bf16x8 av[2], bv[3];
#pragma unroll
    for (int mi = 0; mi < 2; ++mi)
      av[mi] = *(const bf16x8*)(As + (wv * 32 + mi * 16 + rr) * 32 + kb);
#pragma unroll
    for (int ni = 0; ni < 3; ++ni)
      bv[ni] = *(const bf16x8*)(Bs + (ni * 16 + rr) * 32 + kb);
#pragma unroll
    for (int mi = 0; mi < 2; ++mi)
#pragma unroll
      for (int ni = 0; ni < 3; ++ni)
        acc[mi][ni] = __builtin_amdgcn_mfma_f32_16x16x32_bf16(av[mi], bv[ni], acc[mi][ni], 0, 0, 0);
    __syncthreads();
  }
#pragma unroll
  for (int mi = 0; mi < 2; ++mi)
#pragma unroll
    for (int ni = 0; ni < 3; ++ni)
#pragma unroll
      for (int i = 0; i < 4; ++i)
        gl[wv * 32 + mi * 16 + (lane >> 4) * 4 + i][ni * 16 + (lane & 15)] = acc[mi][ni][i];
  __syncthreads();
  if (tid < 128) {
    float g[48];
#pragma unroll
    for (int j = 0; j < 48; ++j) g[j] = gl[tid][j] + pbs[j];
    float cpre = 0.f;
#pragma unroll
    for (int i = 0; i < 4; ++i) {
      float m = fmaxf(fmaxf(g[i * 4], g[i * 4 + 1]), fmaxf(g[i * 4 + 2], g[i * 4 + 3]));
      float e0 = expf(g[i * 4] - m), e1 = expf(g[i * 4 + 1] - m);
      float e2 = expf(g[i * 4 + 2] - m), e3 = expf(g[i * 4 + 3] - m);
      float inv = 1.f / (e0 + e1 + e2 + e3);
      cpre += e0 * inv + e1 * inv + e2 * inv + e3 * inv;
    }
    cpre *= 0.25f;
    float cpost = 0.f;
#pragma unroll
    for (int j = 0; j < 4; ++j) {
      float a0 = g[16 + j], a1 = g[20 + j], a2 = g[24 + j], a3 = g[28 + j];
      float m = fmaxf(fmaxf(a0, a1), fmaxf(a2, a3));
      float e0 = expf(a0 - m), e1 = expf(a1 - m), e2 = expf(a2 - m), e3 = expf(a3 - m);
      float inv = 1.f / (e0 + e1 + e2 + e3);
      cpost += e0 * inv + e1 * inv + e2 * inv + e3 * inv;
    }
    cpost *= 0.25f;
    float w4[16], y4[16];
#pragma unroll
    for (int i = 0; i < 4; ++i)
#pragma unroll
      for (int j = 0; j < 4; ++j)
        w4[i * 4 + j] = g[32 + i * 4 + j] - g[32 + j * 4 + i];
#pragma unroll
    for (int i = 0; i < 16; ++i) y4[i] = 0.1f * w4[i];
    y4[0] += 1.f; y4[5] += 1.f; y4[10] += 1.f; y4[15] += 1.f;
#pragma unroll
    for (int it = 0; it < 2; ++it) {
      float z[16];
#pragma unroll
      for (int i = 0; i < 16; ++i) z[i] = y4[i];
      z[0] += 1.f; z[5] += 1.f; z[10] += 1.f; z[15] += 1.f;
#pragma unroll
      for (int i = 0; i < 4; ++i)
#pragma unroll
        for (int j = 0; j < 4; ++j) {
          float acc2 = 0.f;
#pragma unroll
          for (int k = 0; k < 4; ++k) acc2 += w4[i * 4 + k] * z[k * 4 + j];
          y4[i * 4 + j] = ((i == j) ? 1.f : 0.f) + 0.05f * acc2;
        }
    }
    float cr = 0.f;
#pragma unroll
    for (int i = 0; i < 16; ++i) cr += y4[i];
    cr *= 0.25f;
    cresp[rowBase + tid] = cr;
    cpyp[rowBase + tid] = cpre * cpost;
  }
}

// K4: Y = Xb @ Wt^T; out = cres*xb + cpy*Y (residual read in bf16).
// R5-proven ring verbatim (256x256 tile, 8 waves 2Mx4N, 4-slot K=32 LDS
// ring, depth-3 prefetch, counted vmcnt(8), raw s_barrier 1/slice, verified
// XOR slot-swizzle). ONE functional change vs R5: bn-OUTER XCD mapping --
// XCD x owns exactly one bn column (gid = x*nbm + i -> bn = x, bm = i), so
// the 32 co-resident blocks of an XCD share a single 1MB B-panel
// (L2-resident, 32x reuse) while A streams once per XCD. Replaces the
// bm-major map whose 12MB/XCD working set thrashed the 4MB L2.
__global__ __launch_bounds__(512, 2) void k_gemm(
    const unsigned short* __restrict__ A,   // xb [M][K]
    const unsigned short* __restrict__ Bt,  // Wt [N][K]
    const unsigned short* __restrict__ xbr, // xb again (residual, bf16)
    const float* __restrict__ cresp, const float* __restrict__ cpyp,
    float* __restrict__ out, int M, int N, int K) {
  __shared__ __attribute__((aligned(16))) unsigned short As[4][256 * 32];
  __shared__ __attribute__((aligned(16))) unsigned short Bs[4][256 * 32];
  const int tid = threadIdx.x, lane = tid & 63, wv = tid >> 6;
  const int nbm = M >> 8;                        // 32
  const int nwg = nbm * (N >> 8);                // 256
  const int chunk = nwg >> 3;                    // 32 (nwg % 8 == 0)
  const int gid = (blockIdx.x & 7) * chunk + (blockIdx.x >> 3);
  const int bn = gid / nbm, bm = gid % nbm;      // bn-outer: 1 B-panel per XCD
  const int wm = wv >> 2, wn = wv & 3;
  const int rr = lane & 15, ksl = lane >> 4;
  const int koff = (ksl ^ ((rr >> 1) & 3)) * 8;          // read-side slot swizzle
  const int rloc = tid >> 2;
  const int cbelem = ((tid & 3) ^ ((tid >> 3) & 3)) * 8; // elems within 32
  const unsigned short* aG = A + (size_t)((bm << 8) + rloc) * K + cbelem;
  const unsigned short* bG = Bt + (size_t)((bn << 8) + rloc) * K + cbelem;
  f32x4 acc[8][4] = {};
  const int nsl = K >> 5;                                 // 32-K slices

#define STAGE(KT, SLOT)                                                        \
  {                                                                            \
    const unsigned short* ag_ = aG + (KT) * 32;                                \
    const unsigned short* bg_ = bG + (KT) * 32;                                \
    unsigned short* la_ = &As[(SLOT)][wv * 512];                               \
    unsigned short* lb_ = &Bs[(SLOT)][wv * 512];                               \
    gload_lds16(ag_, la_);                                                     \
    gload_lds16(ag_ + (size_t)128 * K, la_ + 4096);                            \
    gload_lds16(bg_, lb_);                                                     \
    gload_lds16(bg_ + (size_t)128 * K, lb_ + 4096);                            \
  }

  STAGE(0, 0)
  STAGE(1, 1)
  STAGE(2, 2)

#define GBODY(S)                                                               \
  {                                                                            \
    asm volatile("s_waitcnt vmcnt(8)" ::: "memory");                           \
    __builtin_amdgcn_sched_barrier(0);                                         \
    __builtin_amdgcn_s_barrier();                                              \
    __builtin_amdgcn_sched_barrier(0);                                         \
    int kt_ = jb + (S) + 3;                                                    \
    if (kt_ > nsl - 1) kt_ = nsl - 1;                                          \
    STAGE(kt_, ((S) + 3) & 3)                                                  \
    __builtin_amdgcn_sched_barrier(0);                                         \
    const unsigned short* Ab = &As[(S)][(wm * 128 + rr) * 32 + koff];          \
    const unsigned short* Bb = &Bs[(S)][(wn * 64 + rr) * 32 + koff];           \
    bf16x8 av[8], bv[4];                                                       \
    _Pragma("unroll")                                                          \
    for (int mf = 0; mf < 8; ++mf) av[mf] = *(const bf16x8*)(Ab + mf * 512);   \
    _Pragma("unroll")                                                          \
    for (int nf = 0; nf < 4; ++nf) bv[nf] = *(const bf16x8*)(Bb + nf * 512);   \
    __builtin_amdgcn_s_setprio(1);                                             \
    _Pragma("unroll")                                                          \
    for (int mf = 0; mf < 8; ++mf)                                             \
      _Pragma("unroll")                                                        \
      for (int nf = 0; nf < 4; ++nf)                                           \
        acc[mf][nf] =                                                          \
            __builtin_amdgcn_mfma_f32_16x16x32_bf16(av[mf], bv[nf],            \
                                                    acc[mf][nf], 0, 0, 0);     \
    __builtin_amdgcn_s_setprio(0);                                             \
  }

  for (int jb = 0; jb < nsl; jb += 4) {
    GBODY(0)
    GBODY(1)
    GBODY(2)
    GBODY(3)
  }
#undef GBODY
#undef STAGE

  // Epilogue: C/D 16x16 layout col=lane&15, row=(lane>>4)*4 + i (verified)
  const int orow0 = (bm << 8) + wm * 128 + ksl * 4;
  const int ocol0 = (bn << 8) + wn * 64 + rr;
#pragma unroll
  for (int mf = 0; mf < 8; ++mf)
#pragma unroll
    for (int i = 0; i < 4; ++i) {
      const int row = orow0 + mf * 16 + i;
      const float crv = cresp[row], cpv = cpyp[row];
      const size_t base = (size_t)row * N + ocol0;
#pragma unroll
      for (int nf = 0; nf < 4; ++nf)
        out[base + nf * 16] = crv * bf2f(xbr[base + nf * 16]) + cpv * acc[mf][nf][i];
    }
}

extern "C" void kernel_launch(void* const* d_in, const int* in_sizes, int n_in,
                              void* d_out, int out_size, void* d_ws, size_t ws_size,
                              hipStream_t stream) {
  const float* x  = (const float*)d_in[0];
  const float* lw = (const float*)d_in[1];
  const float* lb = (const float*)d_in[2];
  const float* pw = (const float*)d_in[3];
  const float* pb = (const float*)d_in[4];
  const float* W  = (const float*)d_in[5];
  float* out = (float*)d_out;

  const int D = in_sizes[1];           // 2048
  const int M = in_sizes[0] / D;       // 8192 tokens
  const int G = in_sizes[4];           // 48 gates

  char* ws = (char*)d_ws;
  size_t off = 0;
  unsigned short* xb  = (unsigned short*)(ws + off); off += (size_t)M * D * 2;
  unsigned short* lnb = (unsigned short*)(ws + off); off += (size_t)M * D * 2;
  unsigned short* Wt  = (unsigned short*)(ws + off); off += (size_t)D * D * 2;
  unsigned short* pjb = (unsigned short*)(ws + off); off += (size_t)G * D * 2;
  float* cres = (float*)(ws + off); off += (size_t)M * 4;
  float* cpy  = (float*)(ws + off); off += (size_t)M * 4;

  k_ln_conv<<<M, 256, 0, stream>>>(x, lw, lb, xb, lnb, D);
  k_wt<<<dim3(D / 64, D / 64), 256, 0, stream>>>(W, Wt, D);
  k_pconv<<<(G * D / 4 + 255) / 256, 256, 0, stream>>>(pw, pjb, G * D);
  k_gates<<<M / 128, 256, 0, stream>>>(lnb, pjb, pb, cres, cpy, D);

  const int nwg = (M / 256) * (D / 256);
  k_gemm<<<nwg, 512, 0, stream>>>(xb, Wt, xb, cres, cpy, out, M, D, D);
}

// Round 13
// 133.178 us; speedup vs baseline: 1.0580x; 1.0580x over previous
//
#include <hip/hip_runtime.h>
#include <stdint.h>

// out = coeff_res(t) * x + [coeff_pre(t)*coeff_post(t)] * (x @ W_sub)
// coeffs from gates = LN(x) @ proj_w^T + proj_b (48/token), softmax sums + 4x4 Cayley.
// lnb eliminated via: gates_j = r*(x @ (w.P_j)^T) - r*mu*S_j + T_j + pb_j.

typedef __attribute__((ext_vector_type(8))) __bf16 bf16x8;
typedef __attribute__((ext_vector_type(4))) float f32x4;
typedef __attribute__((ext_vector_type(8))) unsigned short us8;
typedef __attribute__((ext_vector_type(4))) unsigned short us4;

__device__ __forceinline__ unsigned short f2bf(float f) {
  union { float f; unsigned int u; } v; v.f = f;
  unsigned int u = v.u;
  u += 0x7fffu + ((u >> 16) & 1u);   // RNE
  return (unsigned short)(u >> 16);
}

__device__ __forceinline__ float bf2f(unsigned short u) {
  union { unsigned int u; float f; } v; v.u = (unsigned int)u << 16;
  return v.f;
}

__device__ __forceinline__ void gload_lds16(const void* g, void* l) {
  __builtin_amdgcn_global_load_lds(
      (__attribute__((address_space(1))) void*)g,
      (__attribute__((address_space(3))) void*)l, 16, 0, 0);
}

// K1: per-token LayerNorm stats (mu, rstd) + write x_bf16. No lnb.
__global__ __launch_bounds__(256) void k_lnx(
    const float* __restrict__ x, unsigned short* __restrict__ xb,
    float2* __restrict__ mur, int D) {
  const int t = blockIdx.x;
  const int tid = threadIdx.x;
  const float* row = x + (size_t)t * D;
  f32x4 a = *(const f32x4*)(row + tid * 8);
  f32x4 b = *(const f32x4*)(row + tid * 8 + 4);
  float vv[8] = {a[0], a[1], a[2], a[3], b[0], b[1], b[2], b[3]};
  float s = 0.f, ss = 0.f;
#pragma unroll
  for (int j = 0; j < 8; ++j) { s += vv[j]; ss += vv[j] * vv[j]; }
#pragma unroll
  for (int off = 32; off > 0; off >>= 1) { s += __shfl_down(s, off); ss += __shfl_down(ss, off); }
  __shared__ float red[8];
  int lane = tid & 63, wv = tid >> 6;
  if (lane == 0) { red[wv] = s; red[4 + wv] = ss; }
  __syncthreads();
  if (tid == 0) {
    float S = red[0] + red[1] + red[2] + red[3];
    float SS = red[4] + red[5] + red[6] + red[7];
    float mu = S / (float)D;
    float var = SS / (float)D - mu * mu;
    float2 o; o.x = mu; o.y = rsqrtf(var + 1e-5f);
    mur[t] = o;
  }
  us8 ox;
#pragma unroll
  for (int j = 0; j < 8; ++j) ox[j] = f2bf(vv[j]);
  *(us8*)(xb + (size_t)t * D + tid * 8) = ox;
}

// K2: W_sub [K][N] fp32 -> Wt [N][K] bf16 (tiled transpose)
__global__ __launch_bounds__(256) void k_wt(const float* __restrict__ W,
                                            unsigned short* __restrict__ Wt, int D) {
  __shared__ float tile[64][65];
  int kb = blockIdx.x * 64, nb = blockIdx.y * 64;
  int tid = threadIdx.x;
  int tx = tid & 15, ty = tid >> 4;
#pragma unroll
  for (int p = 0; p < 4; ++p) {
    int r = p * 16 + ty;
    f32x4 v = *(const f32x4*)(W + (size_t)(kb + r) * D + nb + tx * 4);
    tile[r][tx * 4 + 0] = v[0]; tile[r][tx * 4 + 1] = v[1];
    tile[r][tx * 4 + 2] = v[2]; tile[r][tx * 4 + 3] = v[3];
  }
  __syncthreads();
#pragma unroll
  for (int p = 0; p < 2; ++p) {
    int c = p * 256 + tid;
    int nr = c >> 3, kc = (c & 7) * 8;
    us8 o;
#pragma unroll
    for (int j = 0; j < 8; ++j) o[j] = f2bf(tile[kc + j][nr]);
    *(us8*)(Wt + (size_t)(nb + nr) * D + kb + kc) = o;
  }
}

// K2b: WP[j][k] = f2bf(w[k]*P[j][k]); S[j] = sum_k w[k]*P[j][k];
// T[j] = sum_k b[k]*P[j][k]. One block per j (48 blocks).
__global__ __launch_bounds__(256) void k_wp(
    const float* __restrict__ P, const float* __restrict__ w, const float* __restrict__ b,
    unsigned short* __restrict__ WPb, float* __restrict__ S, float* __restrict__ T, int K) {
  const int j = blockIdx.x, tid = threadIdx.x;
  float s = 0.f, t = 0.f;
  for (int i = tid * 4; i < K; i += 1024) {
    f32x4 pv = *(const f32x4*)(P + (size_t)j * K + i);
    f32x4 wv = *(const f32x4*)(w + i);
    f32x4 bv = *(const f32x4*)(b + i);
    us4 o;
#pragma unroll
    for (int q = 0; q < 4; ++q) {
      float wp = pv[q] * wv[q];
      o[q] = f2bf(wp);
      s += wp;
      t += pv[q] * bv[q];
    }
    *(us4*)(WPb + (size_t)j * K + i) = o;
  }
#pragma unroll
  for (int off = 32; off > 0; off >>= 1) { s += __shfl_down(s, off); t += __shfl_down(t, off); }
  __shared__ float rs[4], rt[4];
  int lane = tid & 63, wvi = tid >> 6;
  if (lane == 0) { rs[wvi] = s; rt[wvi] = t; }
  __syncthreads();
  if (tid == 0) {
    S[j] = rs[0] + rs[1] + rs[2] + rs[3];
    T[j] = rt[0] + rt[1] + rt[2] + rt[3];
  }
}

// K3: dots = xb @ WPb^T via MFMA; gates_j = r*dot - r*mu*S_j + T_j + pb_j;
// then per-token coeff math (validated core, operands swapped to xb/WPb).
__global__ __launch_bounds__(256) void k_gates(
    const unsigned short* __restrict__ A,   // xb [M][K]
    const unsigned short* __restrict__ Bp,  // WPb [48][K]
    const float* __restrict__ pb,
    const float2* __restrict__ mur,
    const float* __restrict__ S, const float* __restrict__ T,
    float* __restrict__ cresp, float* __restrict__ cpyp, int K) {
  __shared__ __attribute__((aligned(16))) unsigned short As[128 * 32];
  __shared__ __attribute__((aligned(16))) unsigned short Bs[48 * 32];
  __shared__ float gl[128][49];
  __shared__ float pbs[48], Ss[48], Ts[48];
  int tid = threadIdx.x, lane = tid & 63, wv = tid >> 6;
  if (tid < 48) { pbs[tid] = pb[tid]; Ss[tid] = S[tid]; Ts[tid] = T[tid]; }
  f32x4 acc[2][3] = {};
  size_t rowBase = (size_t)blockIdx.x * 128;
  for (int k0 = 0; k0 < K; k0 += 32) {
#pragma unroll
    for (int inst = 0; inst < 2; ++inst) {
      int eo = inst * 2048 + wv * 512 + lane * 8;
      int r = eo >> 5, cc = eo & 31;
      gload_lds16(A + (rowBase + r) * K + k0 + cc, (char*)As + inst * 4096 + wv * 1024);
    }
    if (tid < 192) {
      int r = tid >> 2, cc = (tid & 3) * 8;
      us8 v = *(const us8*)(Bp + (size_t)r * K + k0 + cc);
      *(us8*)(Bs + r * 32 + cc) = v;
    }
    __syncthreads();
    int kb = (lane >> 4) * 8, rr = lane & 15;
    bf16x8 av[2], bv[3];
#pragma unroll
    for (int mi = 0; mi < 2; ++mi)
      av[mi] = *(const bf16x8*)(As + (wv * 32 + mi * 16 + rr) * 32 + kb);
#pragma unroll
    for (int ni = 0; ni < 3; ++ni)
      bv[ni] = *(const bf16x8*)(Bs + (ni * 16 + rr) * 32 + kb);
#pragma unroll
    for (int mi = 0; mi < 2; ++mi)
#pragma unroll
      for (int ni = 0; ni < 3; ++ni)
        acc[mi][ni] = __builtin_amdgcn_mfma_f32_16x16x32_bf16(av[mi], bv[ni], acc[mi][ni], 0, 0, 0);
    __syncthreads();
  }
#pragma unroll
  for (int mi = 0; mi < 2; ++mi)
#pragma unroll
    for (int ni = 0; ni < 3; ++ni)
#pragma unroll
      for (int i = 0; i < 4; ++i)
        gl[wv * 32 + mi * 16 + (lane >> 4) * 4 + i][ni * 16 + (lane & 15)] = acc[mi][ni][i];
  __syncthreads();
  if (tid < 128) {
    float2 mr = mur[rowBase + tid];
    const float rmu = mr.y * mr.x;
    float g[48];
#pragma unroll
    for (int j = 0; j < 48; ++j) g[j] = mr.y * gl[tid][j] - rmu * Ss[j] + Ts[j] + pbs[j];
    float cpre = 0.f;
#pragma unroll
    for (int i = 0; i < 4; ++i) {
      float m = fmaxf(fmaxf(g[i * 4], g[i * 4 + 1]), fmaxf(g[i * 4 + 2], g[i * 4 + 3]));
      float e0 = expf(g[i * 4] - m), e1 = expf(g[i * 4 + 1] - m);
      float e2 = expf(g[i * 4 + 2] - m), e3 = expf(g[i * 4 + 3] - m);
      float inv = 1.f / (e0 + e1 + e2 + e3);
      cpre += e0 * inv + e1 * inv + e2 * inv + e3 * inv;
    }
    cpre *= 0.25f;
    float cpost = 0.f;
#pragma unroll
    for (int j = 0; j < 4; ++j) {
      float a0 = g[16 + j], a1 = g[20 + j], a2 = g[24 + j], a3 = g[28 + j];
      float m = fmaxf(fmaxf(a0, a1), fmaxf(a2, a3));
      float e0 = expf(a0 - m), e1 = expf(a1 - m), e2 = expf(a2 - m), e3 = expf(a3 - m);
      float inv = 1.f / (e0 + e1 + e2 + e3);
      cpost += e0 * inv + e1 * inv + e2 * inv + e3 * inv;
    }
    cpost *= 0.25f;
    float w4[16], y4[16];
#pragma unroll
    for (int i = 0; i < 4; ++i)
#pragma unroll
      for (int j = 0; j < 4; ++j)
        w4[i * 4 + j] = g[32 + i * 4 + j] - g[32 + j * 4 + i];
#pragma unroll
    for (int i = 0; i < 16; ++i) y4[i] = 0.1f * w4[i];
    y4[0] += 1.f; y4[5] += 1.f; y4[10] += 1.f; y4[15] += 1.f;
#pragma unroll
    for (int it = 0; it < 2; ++it) {
      float z[16];
#pragma unroll
      for (int i = 0; i < 16; ++i) z[i] = y4[i];
      z[0] += 1.f; z[5] += 1.f; z[10] += 1.f; z[15] += 1.f;
#pragma unroll
      for (int i = 0; i < 4; ++i)
#pragma unroll
        for (int j = 0; j < 4; ++j) {
          float acc2 = 0.f;
#pragma unroll
          for (int k = 0; k < 4; ++k) acc2 += w4[i * 4 + k] * z[k * 4 + j];
          y4[i * 4 + j] = ((i == j) ? 1.f : 0.f) + 0.05f * acc2;
        }
    }
    float cr = 0.f;
#pragma unroll
    for (int i = 0; i < 16; ++i) cr += y4[i];
    cr *= 0.25f;
    cresp[rowBase + tid] = cr;
    cpyp[rowBase + tid] = cpre * cpost;
  }
}

// K4: Y = Xb @ Wt^T; out = cres*xb + cpy*Y (residual read in bf16).
// R12 kernel BYTE-IDENTICAL (best: 88.9 us). 256x256 tile, 8 waves 2Mx4N,
// 4-slot K=32 LDS ring, depth-3 prefetch, counted vmcnt(8), raw s_barrier,
// verified XOR slot-swizzle, bn-outer XCD mapping.
__global__ __launch_bounds__(512, 2) void k_gemm(
    const unsigned short* __restrict__ A,   // xb [M][K]
    const unsigned short* __restrict__ Bt,  // Wt [N][K]
    const unsigned short* __restrict__ xbr, // xb again (residual, bf16)
    const float* __restrict__ cresp, const float* __restrict__ cpyp,
    float* __restrict__ out, int M, int N, int K) {
  __shared__ __attribute__((aligned(16))) unsigned short As[4][256 * 32];
  __shared__ __attribute__((aligned(16))) unsigned short Bs[4][256 * 32];
  const int tid = threadIdx.x, lane = tid & 63, wv = tid >> 6;
  const int nbm = M >> 8;                        // 32
  const int nwg = nbm * (N >> 8);                // 256
  const int chunk = nwg >> 3;                    // 32 (nwg % 8 == 0)
  const int gid = (blockIdx.x & 7) * chunk + (blockIdx.x >> 3);
  const int bn = gid / nbm, bm = gid % nbm;      // bn-outer: 1 B-panel per XCD
  const int wm = wv >> 2, wn = wv & 3;
  const int rr = lane & 15, ksl = lane >> 4;
  const int koff = (ksl ^ ((rr >> 1) & 3)) * 8;          // read-side slot swizzle
  const int rloc = tid >> 2;
  const int cbelem = ((tid & 3) ^ ((tid >> 3) & 3)) * 8; // elems within 32
  const unsigned short* aG = A + (size_t)((bm << 8) + rloc) * K + cbelem;
  const unsigned short* bG = Bt + (size_t)((bn << 8) + rloc) * K + cbelem;
  f32x4 acc[8][4] = {};
  const int nsl = K >> 5;                                 // 32-K slices

#define STAGE(KT, SLOT)                                                        \
  {                                                                            \
    const unsigned short* ag_ = aG + (KT) * 32;                                \
    const unsigned short* bg_ = bG + (KT) * 32;                                \
    unsigned short* la_ = &As[(SLOT)][wv * 512];                               \
    unsigned short* lb_ = &Bs[(SLOT)][wv * 512];                               \
    gload_lds16(ag_, la_);                                                     \
    gload_lds16(ag_ + (size_t)128 * K, la_ + 4096);                            \
    gload_lds16(bg_, lb_);                                                     \
    gload_lds16(bg_ + (size_t)128 * K, lb_ + 4096);                            \
  }

  STAGE(0, 0)
  STAGE(1, 1)
  STAGE(2, 2)

#define GBODY(S)                                                               \
  {                                                                            \
    asm volatile("s_waitcnt vmcnt(8)" ::: "memory");                           \
    __builtin_amdgcn_sched_barrier(0);                                         \
    __builtin_amdgcn_s_barrier();                                              \
    __builtin_amdgcn_sched_barrier(0);                                         \
    int kt_ = jb + (S) + 3;                                                    \
    if (kt_ > nsl - 1) kt_ = nsl - 1;                                          \
    STAGE(kt_, ((S) + 3) & 3)                                                  \
    __builtin_amdgcn_sched_barrier(0);                                         \
    const unsigned short* Ab = &As[(S)][(wm * 128 + rr) * 32 + koff];          \
    const unsigned short* Bb = &Bs[(S)][(wn * 64 + rr) * 32 + koff];           \
    bf16x8 av[8], bv[4];                                                       \
    _Pragma("unroll")                                                          \
    for (int mf = 0; mf < 8; ++mf) av[mf] = *(const bf16x8*)(Ab + mf * 512);   \
    _Pragma("unroll")                                                          \
    for (int nf = 0; nf < 4; ++nf) bv[nf] = *(const bf16x8*)(Bb + nf * 512);   \
    __builtin_amdgcn_s_setprio(1);                                             \
    _Pragma("unroll")                                                          \
    for (int mf = 0; mf < 8; ++mf)                                             \
      _Pragma("unroll")                                                        \
      for (int nf = 0; nf < 4; ++nf)                                           \
        acc[mf][nf] =                                                          \
            __builtin_amdgcn_mfma_f32_16x16x32_bf16(av[mf], bv[nf],            \
                                                    acc[mf][nf], 0, 0, 0);     \
    __builtin_amdgcn_s_setprio(0);                                             \
  }

  for (int jb = 0; jb < nsl; jb += 4) {
    GBODY(0)
    GBODY(1)
    GBODY(2)
    GBODY(3)
  }
#undef GBODY
#undef STAGE

  // Epilogue: C/D 16x16 layout col=lane&15, row=(lane>>4)*4 + i (verified)
  const int orow0 = (bm << 8) + wm * 128 + ksl * 4;
  const int ocol0 = (bn << 8) + wn * 64 + rr;
#pragma unroll
  for (int mf = 0; mf < 8; ++mf)
#pragma unroll
    for (int i = 0; i < 4; ++i) {
      const int row = orow0 + mf * 16 + i;
      const float crv = cresp[row], cpv = cpyp[row];
      const size_t base = (size_t)row * N + ocol0;
#pragma unroll
      for (int nf = 0; nf < 4; ++nf)
        out[base + nf * 16] = crv * bf2f(xbr[base + nf * 16]) + cpv * acc[mf][nf][i];
    }
}

extern "C" void kernel_launch(void* const* d_in, const int* in_sizes, int n_in,
                              void* d_out, int out_size, void* d_ws, size_t ws_size,
                              hipStream_t stream) {
  const float* x  = (const float*)d_in[0];
  const float* lw = (const float*)d_in[1];
  const float* lb = (const float*)d_in[2];
  const float* pw = (const float*)d_in[3];
  const float* pb = (const float*)d_in[4];
  const float* W  = (const float*)d_in[5];
  float* out = (float*)d_out;

  const int D = in_sizes[1];           // 2048
  const int M = in_sizes[0] / D;       // 8192 tokens
  const int G = in_sizes[4];           // 48 gates

  char* ws = (char*)d_ws;
  size_t off = 0;
  unsigned short* xb  = (unsigned short*)(ws + off); off += (size_t)M * D * 2;
  unsigned short* Wt  = (unsigned short*)(ws + off); off += (size_t)D * D * 2;
  unsigned short* WPb = (unsigned short*)(ws + off); off += (size_t)G * D * 2;
  float2* mur = (float2*)(ws + off); off += (size_t)M * 8;
  float* Sv   = (float*)(ws + off); off += 64 * 4;
  float* Tv   = (float*)(ws + off); off += 64 * 4;
  float* cres = (float*)(ws + off); off += (size_t)M * 4;
  float* cpy  = (float*)(ws + off); off += (size_t)M * 4;

  k_lnx<<<M, 256, 0, stream>>>(x, xb, mur, D);
  k_wt<<<dim3(D / 64, D / 64), 256, 0, stream>>>(W, Wt, D);
  k_wp<<<G, 256, 0, stream>>>(pw, lw, lb, WPb, Sv, Tv, D);
  k_gates<<<M / 128, 256, 0, stream>>>(xb, WPb, pb, mur, Sv, Tv, cres, cpy, D);

  const int nwg = (M / 256) * (D / 256);
  k_gemm<<<nwg, 512, 0, stream>>>(xb, Wt, xb, cres, cpy, out, M, D, D);
}

// Round 14
// 116.499 us; speedup vs baseline: 1.2095x; 1.1432x over previous
//
#include <hip/hip_runtime.h>
#include <stdint.h>

// out = coeff_res(t) * x + [coeff_pre(t)*coeff_post(t)] * (x @ W_sub)
// coeffs from gates = LN(x) @ proj_w^T + proj_b (48/token), softmax sums + 4x4 Cayley.
// lnb eliminated: gates_j = r*(x @ (w.P_j)^T) - r*mu*S_j + T_j + pb_j.
// R14: LN-stats + xb-convert + gates-MFMA fused into one 256-block kernel;
// k_wt+k_wp merged. k_gemm byte-identical to R12/R13 best.

typedef __attribute__((ext_vector_type(8))) __bf16 bf16x8;
typedef __attribute__((ext_vector_type(4))) float f32x4;
typedef __attribute__((ext_vector_type(8))) unsigned short us8;
typedef __attribute__((ext_vector_type(4))) unsigned short us4;

__device__ __forceinline__ unsigned short f2bf(float f) {
  union { float f; unsigned int u; } v; v.f = f;
  unsigned int u = v.u;
  u += 0x7fffu + ((u >> 16) & 1u);   // RNE
  return (unsigned short)(u >> 16);
}

__device__ __forceinline__ float bf2f(unsigned short u) {
  union { unsigned int u; float f; } v; v.u = (unsigned int)u << 16;
  return v.f;
}

__device__ __forceinline__ void gload_lds16(const void* g, void* l) {
  __builtin_amdgcn_global_load_lds(
      (__attribute__((address_space(1))) void*)g,
      (__attribute__((address_space(3))) void*)l, 16, 0, 0);
}

// K_WTP: merged weight-prep. Blocks [0, (D/64)^2): W_sub [K][N] fp32 -> Wt
// [N][K] bf16 (tiled transpose). Blocks [(D/64)^2, +48): WP/S/T per gate row.
__global__ __launch_bounds__(256) void k_wtp(
    const float* __restrict__ W, unsigned short* __restrict__ Wt,
    const float* __restrict__ P, const float* __restrict__ w, const float* __restrict__ b,
    unsigned short* __restrict__ WPb, float* __restrict__ S, float* __restrict__ T, int D) {
  __shared__ float tile[64][65];
  __shared__ float rs[4], rt[4];
  const int tid = threadIdx.x;
  const int nwt = (D >> 6) * (D >> 6);
  if ((int)blockIdx.x < nwt) {
    const int bx = blockIdx.x;
    const int kb = (bx & ((D >> 6) - 1)) * 64, nb = (bx / (D >> 6)) * 64;
    const int tx = tid & 15, ty = tid >> 4;
#pragma unroll
    for (int p = 0; p < 4; ++p) {
      int r = p * 16 + ty;
      f32x4 v = *(const f32x4*)(W + (size_t)(kb + r) * D + nb + tx * 4);
      tile[r][tx * 4 + 0] = v[0]; tile[r][tx * 4 + 1] = v[1];
      tile[r][tx * 4 + 2] = v[2]; tile[r][tx * 4 + 3] = v[3];
    }
    __syncthreads();
#pragma unroll
    for (int p = 0; p < 2; ++p) {
      int c = p * 256 + tid;
      int nr = c >> 3, kc = (c & 7) * 8;
      us8 o;
#pragma unroll
      for (int j = 0; j < 8; ++j) o[j] = f2bf(tile[kc + j][nr]);
      *(us8*)(Wt + (size_t)(nb + nr) * D + kb + kc) = o;
    }
  } else {
    const int j = blockIdx.x - nwt;
    float s = 0.f, t = 0.f;
    for (int i = tid * 4; i < D; i += 1024) {
      f32x4 pv = *(const f32x4*)(P + (size_t)j * D + i);
      f32x4 wv = *(const f32x4*)(w + i);
      f32x4 bv = *(const f32x4*)(b + i);
      us4 o;
#pragma unroll
      for (int q = 0; q < 4; ++q) {
        float wp = pv[q] * wv[q];
        o[q] = f2bf(wp);
        s += wp;
        t += pv[q] * bv[q];
      }
      *(us4*)(WPb + (size_t)j * D + i) = o;
    }
#pragma unroll
    for (int off = 32; off > 0; off >>= 1) { s += __shfl_down(s, off); t += __shfl_down(t, off); }
    const int lane = tid & 63, wvi = tid >> 6;
    if (lane == 0) { rs[wvi] = s; rt[wvi] = t; }
    __syncthreads();
    if (tid == 0) {
      S[j] = rs[0] + rs[1] + rs[2] + rs[3];
      T[j] = rt[0] + rt[1] + rt[2] + rt[3];
    }
  }
}

// K_LNGATES: 256 blocks x 32 rows. Per 32-K slice: load x (register-prefetched
// one slice ahead), convert -> xb global + LDS (row stride 40 elems = 80B, so
// b128 fragment reads are <=2-way banked), accumulate per-row sum/sumsq, and
// MFMA the slice against a streamed WPb slice (waves 0,1 only; 16 rows each).
// After the loop: 8-lane shfl stats reduce, then the validated affine +
// softmax + Cayley coefficient epilogue on t<32. Plain __syncthreads only.
__global__ __launch_bounds__(256) void k_lngates(
    const float* __restrict__ x,
    const unsigned short* __restrict__ WPb,  // [48][K]
    const float* __restrict__ pb,
    const float* __restrict__ S, const float* __restrict__ T,
    unsigned short* __restrict__ xb,
    float* __restrict__ cresp, float* __restrict__ cpyp, int K) {
  __shared__ __attribute__((aligned(16))) unsigned short As[32 * 40];
  __shared__ __attribute__((aligned(16))) unsigned short Bs[48 * 40];
  __shared__ float gl[32][49];
  __shared__ float pbs[48], Ss[48], Ts[48];
  __shared__ float smu[32], srd[32];
  const int tid = threadIdx.x, lane = tid & 63, wv = tid >> 6;
  const size_t rowBase = (size_t)blockIdx.x * 32;
  if (tid < 48) { pbs[tid] = pb[tid]; Ss[tid] = S[tid]; Ts[tid] = T[tid]; }
  const int arow = tid >> 3, ac8 = tid & 7;          // 8 threads per row
  const float* gx = x + (rowBase + arow) * (size_t)K + ac8 * 4;
  unsigned short* gxb = xb + (rowBase + arow) * (size_t)K + ac8 * 4;
  const int br = tid >> 2, bc = (tid & 3) * 8;       // 192 threads stage B
  const unsigned short* gB = WPb + (size_t)br * K + bc;
  f32x4 acc[3] = {};                                  // waves 0,1 only
  float s = 0.f, ss = 0.f;
  const int nsl = K >> 5;
  f32x4 xn = *(const f32x4*)gx;
  us8 bn = {};
  if (tid < 192) bn = *(const us8*)gB;
  for (int sl = 0; sl < nsl; ++sl) {
    f32x4 xc = xn;
    us8 bcur = bn;
    if (sl + 1 < nsl) {
      xn = *(const f32x4*)(gx + (sl + 1) * 32);
      if (tid < 192) bn = *(const us8*)(gB + (sl + 1) * 32);
    }
    __syncthreads();                                  // WAR vs prev MFMA reads
    us4 ox;
#pragma unroll
    for (int q = 0; q < 4; ++q) { float v = xc[q]; s += v; ss += v * v; ox[q] = f2bf(v); }
    *(us4*)(As + arow * 40 + ac8 * 4) = ox;
    *(us4*)(gxb + sl * 32) = ox;
    if (tid < 192) *(us8*)(Bs + br * 40 + bc) = bcur;
    __syncthreads();
    if (wv < 2) {
      const int rr = lane & 15, cc2 = (lane >> 4) * 8;
      bf16x8 av = *(const bf16x8*)(As + (wv * 16 + rr) * 40 + cc2);
#pragma unroll
      for (int ni = 0; ni < 3; ++ni) {
        bf16x8 bvf = *(const bf16x8*)(Bs + (ni * 16 + rr) * 40 + cc2);
        acc[ni] = __builtin_amdgcn_mfma_f32_16x16x32_bf16(av, bvf, acc[ni], 0, 0, 0);
      }
    }
  }
  if (wv < 2) {
#pragma unroll
    for (int ni = 0; ni < 3; ++ni)
#pragma unroll
      for (int i = 0; i < 4; ++i)
        gl[wv * 16 + (lane >> 4) * 4 + i][ni * 16 + (lane & 15)] = acc[ni][i];
  }
#pragma unroll
  for (int off = 4; off > 0; off >>= 1) {
    s += __shfl_down(s, off, 8);
    ss += __shfl_down(ss, off, 8);
  }
  if ((tid & 7) == 0) {
    float mu = s / (float)K;
    float var = ss / (float)K - mu * mu;
    smu[arow] = mu;
    srd[arow] = rsqrtf(var + 1e-5f);
  }
  __syncthreads();
  if (tid < 32) {
    const float mu = smu[tid], r = srd[tid], rmu = r * mu;
    float g[48];
#pragma unroll
    for (int j = 0; j < 48; ++j) g[j] = r * gl[tid][j] - rmu * Ss[j] + Ts[j] + pbs[j];
    float cpre = 0.f;
#pragma unroll
    for (int i = 0; i < 4; ++i) {
      float m = fmaxf(fmaxf(g[i * 4], g[i * 4 + 1]), fmaxf(g[i * 4 + 2], g[i * 4 + 3]));
      float e0 = expf(g[i * 4] - m), e1 = expf(g[i * 4 + 1] - m);
      float e2 = expf(g[i * 4 + 2] - m), e3 = expf(g[i * 4 + 3] - m);
      float inv = 1.f / (e0 + e1 + e2 + e3);
      cpre += e0 * inv + e1 * inv + e2 * inv + e3 * inv;
    }
    cpre *= 0.25f;
    float cpost = 0.f;
#pragma unroll
    for (int j = 0; j < 4; ++j) {
      float a0 = g[16 + j], a1 = g[20 + j], a2 = g[24 + j], a3 = g[28 + j];
      float m = fmaxf(fmaxf(a0, a1), fmaxf(a2, a3));
      float e0 = expf(a0 - m), e1 = expf(a1 - m), e2 = expf(a2 - m), e3 = expf(a3 - m);
      float inv = 1.f / (e0 + e1 + e2 + e3);
      cpost += e0 * inv + e1 * inv + e2 * inv + e3 * inv;
    }
    cpost *= 0.25f;
    float w4[16], y4[16];
#pragma unroll
    for (int i = 0; i < 4; ++i)
#pragma unroll
      for (int j = 0; j < 4; ++j)
        w4[i * 4 + j] = g[32 + i * 4 + j] - g[32 + j * 4 + i];
#pragma unroll
    for (int i = 0; i < 16; ++i) y4[i] = 0.1f * w4[i];
    y4[0] += 1.f; y4[5] += 1.f; y4[10] += 1.f; y4[15] += 1.f;
#pragma unroll
    for (int it = 0; it < 2; ++it) {
      float z[16];
#pragma unroll
      for (int i = 0; i < 16; ++i) z[i] = y4[i];
      z[0] += 1.f; z[5] += 1.f; z[10] += 1.f; z[15] += 1.f;
#pragma unroll
      for (int i = 0; i < 4; ++i)
#pragma unroll
        for (int j = 0; j < 4; ++j) {
          float acc2 = 0.f;
#pragma unroll
          for (int k = 0; k < 4; ++k) acc2 += w4[i * 4 + k] * z[k * 4 + j];
          y4[i * 4 + j] = ((i == j) ? 1.f : 0.f) + 0.05f * acc2;
        }
    }
    float cr = 0.f;
#pragma unroll
    for (int i = 0; i < 16; ++i) cr += y4[i];
    cr *= 0.25f;
    cresp[rowBase + tid] = cr;
    cpyp[rowBase + tid] = cpre * cpost;
  }
}

// K4: Y = Xb @ Wt^T; out = cres*xb + cpy*Y (residual read in bf16).
// BYTE-IDENTICAL to R12/R13 best (88.9 us). 256x256 tile, 8 waves 2Mx4N,
// 4-slot K=32 LDS ring, depth-3 prefetch, counted vmcnt(8), raw s_barrier,
// verified XOR slot-swizzle, bn-outer XCD mapping.
__global__ __launch_bounds__(512, 2) void k_gemm(
    const unsigned short* __restrict__ A,   // xb [M][K]
    const unsigned short* __restrict__ Bt,  // Wt [N][K]
    const unsigned short* __restrict__ xbr, // xb again (residual, bf16)
    const float* __restrict__ cresp, const float* __restrict__ cpyp,
    float* __restrict__ out, int M, int N, int K) {
  __shared__ __attribute__((aligned(16))) unsigned short As[4][256 * 32];
  __shared__ __attribute__((aligned(16))) unsigned short Bs[4][256 * 32];
  const int tid = threadIdx.x, lane = tid & 63, wv = tid >> 6;
  const int nbm = M >> 8;                        // 32
  const int nwg = nbm * (N >> 8);                // 256
  const int chunk = nwg >> 3;                    // 32 (nwg % 8 == 0)
  const int gid = (blockIdx.x & 7) * chunk + (blockIdx.x >> 3);
  const int bn = gid / nbm, bm = gid % nbm;      // bn-outer: 1 B-panel per XCD
  const int wm = wv >> 2, wn = wv & 3;
  const int rr = lane & 15, ksl = lane >> 4;
  const int koff = (ksl ^ ((rr >> 1) & 3)) * 8;          // read-side slot swizzle
  const int rloc = tid >> 2;
  const int cbelem = ((tid & 3) ^ ((tid >> 3) & 3)) * 8; // elems within 32
  const unsigned short* aG = A + (size_t)((bm << 8) + rloc) * K + cbelem;
  const unsigned short* bG = Bt + (size_t)((bn << 8) + rloc) * K + cbelem;
  f32x4 acc[8][4] = {};
  const int nsl = K >> 5;                                 // 32-K slices

#define STAGE(KT, SLOT)                                                        \
  {                                                                            \
    const unsigned short* ag_ = aG + (KT) * 32;                                \
    const unsigned short* bg_ = bG + (KT) * 32;                                \
    unsigned short* la_ = &As[(SLOT)][wv * 512];                               \
    unsigned short* lb_ = &Bs[(SLOT)][wv * 512];                               \
    gload_lds16(ag_, la_);                                                     \
    gload_lds16(ag_ + (size_t)128 * K, la_ + 4096);                            \
    gload_lds16(bg_, lb_);                                                     \
    gload_lds16(bg_ + (size_t)128 * K, lb_ + 4096);                            \
  }

  STAGE(0, 0)
  STAGE(1, 1)
  STAGE(2, 2)

#define GBODY(S)                                                               \
  {                                                                            \
    asm volatile("s_waitcnt vmcnt(8)" ::: "memory");                           \
    __builtin_amdgcn_sched_barrier(0);                                         \
    __builtin_amdgcn_s_barrier();                                              \
    __builtin_amdgcn_sched_barrier(0);                                         \
    int kt_ = jb + (S) + 3;                                                    \
    if (kt_ > nsl - 1) kt_ = nsl - 1;                                          \
    STAGE(kt_, ((S) + 3) & 3)                                                  \
    __builtin_amdgcn_sched_barrier(0);                                         \
    const unsigned short* Ab = &As[(S)][(wm * 128 + rr) * 32 + koff];          \
    const unsigned short* Bb = &Bs[(S)][(wn * 64 + rr) * 32 + koff];           \
    bf16x8 av[8], bv[4];                                                       \
    _Pragma("unroll")                                                          \
    for (int mf = 0; mf < 8; ++mf) av[mf] = *(const bf16x8*)(Ab + mf * 512);   \
    _Pragma("unroll")                                                          \
    for (int nf = 0; nf < 4; ++nf) bv[nf] = *(const bf16x8*)(Bb + nf * 512);   \
    __builtin_amdgcn_s_setprio(1);                                             \
    _Pragma("unroll")                                                          \
    for (int mf = 0; mf < 8; ++mf)                                             \
      _Pragma("unroll")                                                        \
      for (int nf = 0; nf < 4; ++nf)                                           \
        acc[mf][nf] =                                                          \
            __builtin_amdgcn_mfma_f32_16x16x32_bf16(av[mf], bv[nf],            \
                                                    acc[mf][nf], 0, 0, 0);     \
    __builtin_amdgcn_s_setprio(0);                                             \
  }

  for (int jb = 0; jb < nsl; jb += 4) {
    GBODY(0)
    GBODY(1)
    GBODY(2)
    GBODY(3)
  }
#undef GBODY
#undef STAGE

  // Epilogue: C/D 16x16 layout col=lane&15, row=(lane>>4)*4 + i (verified)
  const int orow0 = (bm << 8) + wm * 128 + ksl * 4;
  const int ocol0 = (bn << 8) + wn * 64 + rr;
#pragma unroll
  for (int mf = 0; mf < 8; ++mf)
#pragma unroll
    for (int i = 0; i < 4; ++i) {
      const int row = orow0 + mf * 16 + i;
      const float crv = cresp[row], cpv = cpyp[row];
      const size_t base = (size_t)row * N + ocol0;
#pragma unroll
      for (int nf = 0; nf < 4; ++nf)
        out[base + nf * 16] = crv * bf2f(xbr[base + nf * 16]) + cpv * acc[mf][nf][i];
    }
}

extern "C" void kernel_launch(void* const* d_in, const int* in_sizes, int n_in,
                              void* d_out, int out_size, void* d_ws, size_t ws_size,
                              hipStream_t stream) {
  const float* x  = (const float*)d_in[0];
  const float* lw = (const float*)d_in[1];
  const float* lb = (const float*)d_in[2];
  const float* pw = (const float*)d_in[3];
  const float* pb = (const float*)d_in[4];
  const float* W  = (const float*)d_in[5];
  float* out = (float*)d_out;

  const int D = in_sizes[1];           // 2048
  const int M = in_sizes[0] / D;       // 8192 tokens
  const int G = in_sizes[4];           // 48 gates

  char* ws = (char*)d_ws;
  size_t off = 0;
  unsigned short* xb  = (unsigned short*)(ws + off); off += (size_t)M * D * 2;
  unsigned short* Wt  = (unsigned short*)(ws + off); off += (size_t)D * D * 2;
  unsigned short* WPb = (unsigned short*)(ws + off); off += (size_t)G * D * 2;
  float* Sv   = (float*)(ws + off); off += 64 * 4;
  float* Tv   = (float*)(ws + off); off += 64 * 4;
  float* cres = (float*)(ws + off); off += (size_t)M * 4;
  float* cpy  = (float*)(ws + off); off += (size_t)M * 4;

  const int nwt = (D / 64) * (D / 64);
  k_wtp<<<nwt + G, 256, 0, stream>>>(W, Wt, pw, lw, lb, WPb, Sv, Tv, D);
  k_lngates<<<M / 32, 256, 0, stream>>>(x, WPb, pb, Sv, Tv, xb, cres, cpy, D);

  const int nwg = (M / 256) * (D / 256);
  k_gemm<<<nwg, 512, 0, stream>>>(xb, Wt, xb, cres, cpy, out, M, D, D);
}